// Round 1
// baseline (166.263 us; speedup 1.0000x reference)
//
#include <hip/hip_runtime.h>
#include <math.h>

// SSIM loss, fused. Inputs: pred, target fp32 (64,1,512,512). Output: scalar fp32.
//
// S = u(X)+u(Y), D = u(X)-u(Y);  4 blurred channels:
//   muS=blur(S), muD=blur(D), PS=blur(S^2), PD=blur(D^2)
//   ssim = [(muS^2-muD^2+2C1)/(muS^2+muD^2+2C1)] * [(PS-muS^2-PD+muD^2+2C2)/(PS-muS^2+PD-muD^2+2C2)]
//
// R3: pk_fma float2 pairs, BAND 64/RY 8, 2 barriers/chunk.        63 us, VGPR 60
// R4/R5: launch_bounds min-waves>=6 => allocator spills. Never again.
// R6: BAND 32/RY 4 but KEPT 66KB dbuf -> still 2 blocks/CU, occupancy 37%, 72.5 us.
//   => lesson: occupancy was LDS-capped, not grid-capped.
// R7: single-barrier ping-pong pipeline, BAND 64, RY 4, 66KB. 63.8 us.
//   Counters: VALUBusy 52%, Occupancy 33%, HBM 15% -> latency/overlap-bound,
//   no pipe saturated. VALU floor ~26-33us, LDS-unit ~24us; they serialize.
// R8 (this): SINGLE 33KB buffer + 2 barriers/chunk (R3 showed 2-bar ~ 1-bar),
//   BAND 32, grid(16,64)=1024 blocks -> 4 blocks/CU * 8 waves = 32 waves/CU
//   (100% occupancy cap; 2048 thr/CU exactly). VGPR 52 <= 64 so 8 waves/SIMD
//   fit. Goal: overlap VALU + LDS + global latency across 4 independent
//   blocks/CU. Accept +1 barrier/chunk and 31% ring halo redundancy (L3-served).

typedef float v2f __attribute__((ext_vector_type(2)));

#define WIN 11
#define IMG 512
#define OUTW 502            // 512 - 11 + 1
#define BAND 32             // output rows per block
#define RY 4                // output rows per chunk
#define NCHUNK (BAND / RY)  // 8
#define COLS2 516           // float2 columns per row (512 + 4 pad)

constexpr float A_SC  = 8.0f / 37.0f;           // std / (max-min)
constexpr float TWO_B = 2.0f * (15.5f / 37.0f); // 2*(mean-min)/(max-min)
constexpr float TWO_C1 = 2.0f * 1e-4f;
constexpr float TWO_C2 = 2.0f * 9e-4f;

__global__ __launch_bounds__(512, 4)
void ssim_main(const float* __restrict__ X, const float* __restrict__ Y,
               float* __restrict__ ws)
{
    // SINGLE buffer: 2 pair-channels * 4 rows * 516 cols * 8B = 33,024 B
    // -> 4 blocks/CU (133KB of 160KB), vs R7's 66KB dbuf -> 2 blocks/CU.
    __shared__ __align__(16) v2f sP[2][RY][COLS2];
    __shared__ float sW[WIN];
    __shared__ float sRed[8];

    const int tid  = threadIdx.x;
    const int band = blockIdx.x;
    const int b    = blockIdx.y;
    const int y0   = band * BAND;

    if (tid == 0) {
        double g[WIN]; double sum = 0.0;
        for (int k = 0; k < WIN; ++k) { double c = k - 5; g[k] = exp(-(c * c) / 4.5); sum += g[k]; }
        for (int k = 0; k < WIN; ++k) sW[k] = (float)(g[k] / sum);
    }
    __syncthreads();
    // Wave-uniform weights -> SGPRs (v_pk_fma_f32 may read 1 SGPR operand)
    float w[WIN];
    #pragma unroll
    for (int k = 0; k < WIN; ++k)
        w[k] = __uint_as_float(__builtin_amdgcn_readfirstlane(__float_as_uint(sW[k])));

    const float* __restrict__ Xb = X + (size_t)b * (IMG * (size_t)IMG);
    const float* __restrict__ Yb = Y + (size_t)b * (IMG * (size_t)IMG);

    const int x  = tid;              // column owned in vertical pass
    const int r  = tid >> 7;         // horizontal: row slot (0..3)
    const int gi = (tid >> 6) & 1;   // horizontal: column-group slot
    const int s  = tid & 63;
    const int x0 = 4 * (s + 64 * gi);

    float acc = 0.0f;

    // Rolling prep ring: psd[i] = {s,d} of row (nbase + i), i=0..9, where
    // nbase is the base row of the NEXT chunk to be vertical-blurred.
    // y0+9 <= 489 < 512 always, no clamp needed here.
    v2f psd[10];
    #pragma unroll
    for (int i = 0; i < 10; ++i) {
        const uint32_t idx = (uint32_t)(y0 + i) * IMG + (uint32_t)x;
        const float xv = Xb[idx], yv = Yb[idx];
        v2f t; t.x = fmaf(xv + yv, A_SC, TWO_B); t.y = (xv - yv) * A_SC;
        psd[i] = t;
    }

    // c = -1: prologue (vertical chunk 0 only). c = 0..7: horizontal c (+ vertical c+1).
    // Single buffer, two barriers per chunk:
    //   [loads c+1 issued] [H reads chunk c] --WAR barrier-- [V writes c+1] --RAW barrier--
    #pragma unroll 1
    for (int c = -1; c < NCHUNK; ++c) {
        const int vchunk = c + 1;               // chunk to vertical-blur this iter
        const bool dovert = (vchunk < NCHUNK);
        const int nbase = y0 + vchunk * RY;

        // ---- (a) issue fresh-row global loads for chunk c+1 early
        float fx[RY], fy[RY];
        if (dovert) {
            #pragma unroll
            for (int jj = 0; jj < RY; ++jj) {
                int yi = nbase + 10 + jj; yi = yi < IMG - 1 ? yi : IMG - 1; // clamp feeds masked rows only
                const uint32_t idx = (uint32_t)yi * IMG + (uint32_t)x;
                fx[jj] = Xb[idx]; fy[jj] = Yb[idx];
            }
        }

        // ---- (b) horizontal chunk c from sP (written last iteration)
        if (c >= 0) {
            const int ybase = y0 + c * RY;
            const int yo = ybase + r;
            if (yo < OUTW && x0 < OUTW) {
                v2f Hsd[4], Hq[4];
                #pragma unroll
                for (int p = 0; p < 2; ++p) {
                    v2f a0 = (v2f)0.0f, a1 = (v2f)0.0f, a2 = (v2f)0.0f, a3 = (v2f)0.0f;
                    const float4* q4 = (const float4*)&sP[p][r][x0];
                    #pragma unroll
                    for (int j4 = 0; j4 < 7; ++j4) {
                        const float4 qq = q4[j4];
                        #pragma unroll
                        for (int h = 0; h < 2; ++h) {
                            const int j = 2 * j4 + h;
                            v2f col; col.x = h ? qq.z : qq.x; col.y = h ? qq.w : qq.y;
                            if (j - 0 >= 0 && j - 0 < WIN) a0 += w[j]     * col;
                            if (j - 1 >= 0 && j - 1 < WIN) a1 += w[j - 1] * col;
                            if (j - 2 >= 0 && j - 2 < WIN) a2 += w[j - 2] * col;
                            if (j - 3 >= 0 && j - 3 < WIN) a3 += w[j - 3] * col;
                        }
                    }
                    if (p == 0) { Hsd[0] = a0; Hsd[1] = a1; Hsd[2] = a2; Hsd[3] = a3; }
                    else        { Hq[0]  = a0; Hq[1]  = a1; Hq[2]  = a2; Hq[3]  = a3; }
                }
                #pragma unroll
                for (int i = 0; i < 4; ++i) {
                    if (x0 + i < OUTW) {
                        const v2f m2 = Hsd[i] * Hsd[i];   // {mS2, mD2}
                        const v2f sg = Hq[i] - m2;        // {sS, sD}
                        const float na = m2.x - m2.y + TWO_C1;
                        const float da = m2.x + m2.y + TWO_C1;
                        const float nb = sg.x - sg.y + TWO_C2;
                        const float db = sg.x + sg.y + TWO_C2;
                        acc = fmaf(na * nb, __builtin_amdgcn_rcpf(da * db), acc);
                    }
                }
            }
        }

        // ---- WAR barrier: all readers of chunk c done before overwriting buffer
        if (c >= 0 && dovert) __syncthreads();

        // ---- (c) vertical chunk c+1 -> sP (single buffer)
        if (dovert) {
            v2f vsd[RY], vq[RY];
            #pragma unroll
            for (int rr = 0; rr < RY; ++rr) { vsd[rr] = (v2f)0.0f; vq[rr] = (v2f)0.0f; }

            // kept rows j = 0..9 (from ring, rows nbase..nbase+9)
            #pragma unroll
            for (int j = 0; j < 10; ++j) {
                const v2f a = psd[j];
                const v2f q = a * a;
                #pragma unroll
                for (int rr = 0; rr < RY; ++rr) {
                    const int k = j - rr;
                    if (k >= 0 && k < WIN) {
                        const float wk = w[k];
                        vsd[rr] += wk * a;   // -> v_pk_fma_f32
                        vq[rr]  += wk * q;
                    }
                }
            }
            // fresh rows j = 10..13 from the early loads
            v2f nw[RY];
            #pragma unroll
            for (int jj = 0; jj < RY; ++jj) {
                const int j = 10 + jj;
                v2f a; a.x = fmaf(fx[jj] + fy[jj], A_SC, TWO_B); a.y = (fx[jj] - fy[jj]) * A_SC;
                const v2f q = a * a;
                #pragma unroll
                for (int rr = 0; rr < RY; ++rr) {
                    const int k = j - rr;
                    if (k >= 0 && k < WIN) {
                        const float wk = w[k];
                        vsd[rr] += wk * a;
                        vq[rr]  += wk * q;
                    }
                }
                nw[jj] = a;
            }
            // rotate ring by RY
            #pragma unroll
            for (int i = 0; i < 10 - RY; ++i) psd[i] = psd[i + RY];
            #pragma unroll
            for (int i = 0; i < RY; ++i) psd[10 - RY + i] = nw[i];

            #pragma unroll
            for (int rr = 0; rr < RY; ++rr) {
                sP[0][rr][x] = vsd[rr];  // ds_write_b64, conflict-free
                sP[1][rr][x] = vq[rr];
            }
            __syncthreads();   // RAW barrier: writes of chunk c+1 visible
        }
    }

    // block reduction -> one atomic per image
    #pragma unroll
    for (int off = 32; off > 0; off >>= 1) acc += __shfl_down(acc, off, 64);
    if ((tid & 63) == 0) sRed[tid >> 6] = acc;
    __syncthreads();
    if (tid == 0) {
        float t = 0.f;
        #pragma unroll
        for (int i = 0; i < 8; ++i) t += sRed[i];
        atomicAdd(&ws[b], t);
    }
}

__global__ void ssim_finalize(const float* __restrict__ ws, float* __restrict__ out)
{
    const int t = threadIdx.x; // one wave
    float v = ws[t] * (1.0f / (502.0f * 502.0f));
    v = v > 0.f ? v : 0.f;     // relu(per-image mean)
    #pragma unroll
    for (int off = 32; off > 0; off >>= 1) v += __shfl_down(v, off, 64);
    if (t == 0) out[0] = v * (1.0f / 64.0f);
}

extern "C" void kernel_launch(void* const* d_in, const int* in_sizes, int n_in,
                              void* d_out, int out_size, void* d_ws, size_t ws_size,
                              hipStream_t stream)
{
    const float* pred   = (const float*)d_in[0];
    const float* target = (const float*)d_in[1];
    float* out = (float*)d_out;
    float* ws  = (float*)d_ws;

    hipMemsetAsync(ws, 0, 64 * sizeof(float), stream);  // ws poisoned 0xAA each call
    ssim_main<<<dim3(16, 64), 512, 0, stream>>>(pred, target, ws);
    ssim_finalize<<<1, 64, 0, stream>>>(ws, out);
}

// Round 3
// 159.676 us; speedup vs baseline: 1.0413x; 1.0413x over previous
//
#include <hip/hip_runtime.h>
#include <math.h>

// SSIM loss, fused. Inputs: pred, target fp32 (64,1,512,512). Output: scalar fp32.
//
// S = u(X)+u(Y), D = u(X)-u(Y);  4 blurred channels:
//   muS=blur(S), muD=blur(D), PS=blur(S^2), PD=blur(D^2)
//   ssim = [(muS^2-muD^2+2C1)/(muS^2+muD^2+2C1)] * [(PS-muS^2-PD+muD^2+2C2)/(PS-muS^2+PD-muD^2+2C2)]
//
// R3: pk_fma float2 pairs, BAND 64/RY 8, 2 barriers/chunk.        63 us, VGPR 60
// R4/R5: launch_bounds min-waves>=6 => allocator spills. Never again.
// R6: BAND 32/RY 4 kept 66KB dbuf -> still 2 blocks/CU, 72.5 us.
// R7: single-barrier ping-pong, BAND 64, 66KB, 2 blocks/CU. 63.8 us.
// R8: single 33KB buf, BAND 32, grid 1024 = 4 blocks/CU possible. 65.6 us.
//   => Occupancy ~34% and VALUBusy ~51% IDENTICAL to R7. Perf invariant to
//      resident-wave cap. Loss is inside the barrier-locked phase structure.
// R9: V-compute hoisted above H + finalize fused via last-block counter at
//   ws[64]. CONTAINER FAILED TWICE — suspect OOB write past 64-float
//   workspace (ws[64] counter + 65-float memset). Fusion reverted; never
//   touch ws beyond 64 floats without knowing ws_size.
// R9b (this): V-hoist ONLY, two-kernel structure restored. Order per chunk:
//   loads(c+1) -> V-partial(ring FMAs, no LDS) + rotate -> H(c) ->
//   V-fresh(loaded rows) -> WAR bar -> LDS writes -> RAW bar.
//   Only ~40cy of ds_write between barriers; H's ds_read shadows can be
//   filled with V's independent FMAs. launch_bounds (512,2): V accums live
//   across H => ~72 VGPR; forcing <=64 risks the R4/R5 spill trap.

typedef float v2f __attribute__((ext_vector_type(2)));

#define WIN 11
#define IMG 512
#define OUTW 502            // 512 - 11 + 1
#define BAND 64             // output rows per block
#define RY 4                // output rows per chunk
#define NCHUNK (BAND / RY)  // 16
#define COLS2 516           // float2 columns per row (512 + 4 pad)

constexpr float A_SC  = 8.0f / 37.0f;           // std / (max-min)
constexpr float TWO_B = 2.0f * (15.5f / 37.0f); // 2*(mean-min)/(max-min)
constexpr float TWO_C1 = 2.0f * 1e-4f;
constexpr float TWO_C2 = 2.0f * 9e-4f;

__global__ __launch_bounds__(512, 2)
void ssim_main(const float* __restrict__ X, const float* __restrict__ Y,
               float* __restrict__ ws)
{
    // single buffer: 2 pair-channels * 4 rows * 516 cols * 8B = 33,024 B
    __shared__ __align__(16) v2f sP[2][RY][COLS2];
    __shared__ float sW[WIN];
    __shared__ float sRed[8];

    const int tid  = threadIdx.x;
    const int band = blockIdx.x;
    const int b    = blockIdx.y;
    const int y0   = band * BAND;

    if (tid == 0) {
        double g[WIN]; double sum = 0.0;
        for (int k = 0; k < WIN; ++k) { double c = k - 5; g[k] = exp(-(c * c) / 4.5); sum += g[k]; }
        for (int k = 0; k < WIN; ++k) sW[k] = (float)(g[k] / sum);
    }
    __syncthreads();
    // Wave-uniform weights -> SGPRs (v_pk_fma_f32 may read 1 SGPR operand)
    float w[WIN];
    #pragma unroll
    for (int k = 0; k < WIN; ++k)
        w[k] = __uint_as_float(__builtin_amdgcn_readfirstlane(__float_as_uint(sW[k])));

    const float* __restrict__ Xb = X + (size_t)b * (IMG * (size_t)IMG);
    const float* __restrict__ Yb = Y + (size_t)b * (IMG * (size_t)IMG);

    const int x  = tid;              // column owned in vertical pass
    const int r  = tid >> 7;         // horizontal: row slot (0..3)
    const int gi = (tid >> 6) & 1;   // horizontal: column-group slot
    const int s  = tid & 63;
    const int x0 = 4 * (s + 64 * gi);

    float acc = 0.0f;

    // Rolling prep ring: psd[i] = {s,d} of row (nbase + i), i=0..9, where
    // nbase is the base row of the NEXT chunk to be vertical-blurred.
    v2f psd[10];
    #pragma unroll
    for (int i = 0; i < 10; ++i) {
        const uint32_t idx = (uint32_t)(y0 + i) * IMG + (uint32_t)x;
        const float xv = Xb[idx], yv = Yb[idx];
        v2f t; t.x = fmaf(xv + yv, A_SC, TWO_B); t.y = (xv - yv) * A_SC;
        psd[i] = t;
    }

    // c = -1: prologue (vertical chunk 0 only). c = 0..15: horizontal c (+ vertical c+1).
    // Per iter: loads(c+1) -> V-partial(ring) -> H(c) -> V-fresh -> WAR bar -> writes -> RAW bar
    #pragma unroll 1
    for (int c = -1; c < NCHUNK; ++c) {
        const int vchunk = c + 1;               // chunk to vertical-blur this iter
        const bool dovert = (vchunk < NCHUNK);
        const int nbase = y0 + vchunk * RY;

        // ---- (a) issue fresh-row global loads for chunk c+1 early
        float fx[RY], fy[RY];
        if (dovert) {
            #pragma unroll
            for (int jj = 0; jj < RY; ++jj) {
                int yi = nbase + 10 + jj; yi = yi < IMG - 1 ? yi : IMG - 1; // clamp feeds masked rows only
                const uint32_t idx = (uint32_t)yi * IMG + (uint32_t)x;
                fx[jj] = Xb[idx]; fy[jj] = Yb[idx];
            }
        }

        // ---- (a2) V-partial: kept ring rows j = 0..9 (pure register FMAs, no LDS).
        // Independent of H below; scheduler can fill H's ds_read shadows with these.
        v2f vsd[RY], vq[RY];
        if (dovert) {
            #pragma unroll
            for (int rr = 0; rr < RY; ++rr) { vsd[rr] = (v2f)0.0f; vq[rr] = (v2f)0.0f; }
            #pragma unroll
            for (int j = 0; j < 10; ++j) {
                const v2f a = psd[j];
                const v2f q = a * a;
                #pragma unroll
                for (int rr = 0; rr < RY; ++rr) {
                    const int k = j - rr;
                    if (k >= 0 && k < WIN) {
                        const float wk = w[k];
                        vsd[rr] += wk * a;   // -> v_pk_fma_f32
                        vq[rr]  += wk * q;
                    }
                }
            }
            // rotate ring now: rows nbase+4..nbase+9 -> slots 0..5
            #pragma unroll
            for (int i = 0; i < 10 - RY; ++i) psd[i] = psd[i + RY];
        }

        // ---- (b) horizontal chunk c from sP (written last iteration)
        if (c >= 0) {
            const int ybase = y0 + c * RY;
            const int yo = ybase + r;
            if (yo < OUTW && x0 < OUTW) {
                v2f Hsd[4], Hq[4];
                #pragma unroll
                for (int p = 0; p < 2; ++p) {
                    v2f a0 = (v2f)0.0f, a1 = (v2f)0.0f, a2 = (v2f)0.0f, a3 = (v2f)0.0f;
                    const float4* q4 = (const float4*)&sP[p][r][x0];
                    #pragma unroll
                    for (int j4 = 0; j4 < 7; ++j4) {
                        const float4 qq = q4[j4];
                        #pragma unroll
                        for (int h = 0; h < 2; ++h) {
                            const int j = 2 * j4 + h;
                            v2f col; col.x = h ? qq.z : qq.x; col.y = h ? qq.w : qq.y;
                            if (j - 0 >= 0 && j - 0 < WIN) a0 += w[j]     * col;
                            if (j - 1 >= 0 && j - 1 < WIN) a1 += w[j - 1] * col;
                            if (j - 2 >= 0 && j - 2 < WIN) a2 += w[j - 2] * col;
                            if (j - 3 >= 0 && j - 3 < WIN) a3 += w[j - 3] * col;
                        }
                    }
                    if (p == 0) { Hsd[0] = a0; Hsd[1] = a1; Hsd[2] = a2; Hsd[3] = a3; }
                    else        { Hq[0]  = a0; Hq[1]  = a1; Hq[2]  = a2; Hq[3]  = a3; }
                }
                #pragma unroll
                for (int i = 0; i < 4; ++i) {
                    if (x0 + i < OUTW) {
                        const v2f m2 = Hsd[i] * Hsd[i];   // {mS2, mD2}
                        const v2f sg = Hq[i] - m2;        // {sS, sD}
                        const float na = m2.x - m2.y + TWO_C1;
                        const float da = m2.x + m2.y + TWO_C1;
                        const float nb = sg.x - sg.y + TWO_C2;
                        const float db = sg.x + sg.y + TWO_C2;
                        acc = fmaf(na * nb, __builtin_amdgcn_rcpf(da * db), acc);
                    }
                }
            }
        }

        // ---- (b2) V-fresh: rows j = 10..13 from the early loads (vmcnt waits
        // land here, after ~H's worth of latency shadow)
        if (dovert) {
            #pragma unroll
            for (int jj = 0; jj < RY; ++jj) {
                const int j = 10 + jj;
                v2f a; a.x = fmaf(fx[jj] + fy[jj], A_SC, TWO_B); a.y = (fx[jj] - fy[jj]) * A_SC;
                const v2f q = a * a;
                #pragma unroll
                for (int rr = 0; rr < RY; ++rr) {
                    const int k = j - rr;
                    if (k >= 0 && k < WIN) {
                        const float wk = w[k];
                        vsd[rr] += wk * a;
                        vq[rr]  += wk * q;
                    }
                }
                psd[10 - RY + jj] = a;   // ring slots 6..9
            }
        }

        // ---- WAR barrier: all readers of chunk c done before overwriting buffer.
        // Only the LDS writes (~40cy) sit between the barriers now.
        if (c >= 0 && dovert) __syncthreads();

        if (dovert) {
            #pragma unroll
            for (int rr = 0; rr < RY; ++rr) {
                sP[0][rr][x] = vsd[rr];  // ds_write_b64, conflict-free
                sP[1][rr][x] = vq[rr];
            }
            __syncthreads();   // RAW barrier: writes of chunk c+1 visible
        }
    }

    // block reduction -> one atomic per image
    #pragma unroll
    for (int off = 32; off > 0; off >>= 1) acc += __shfl_down(acc, off, 64);
    if ((tid & 63) == 0) sRed[tid >> 6] = acc;
    __syncthreads();
    if (tid == 0) {
        float t = 0.f;
        #pragma unroll
        for (int i = 0; i < 8; ++i) t += sRed[i];
        atomicAdd(&ws[b], t);
    }
}

__global__ void ssim_finalize(const float* __restrict__ ws, float* __restrict__ out)
{
    const int t = threadIdx.x; // one wave
    float v = ws[t] * (1.0f / (502.0f * 502.0f));
    v = v > 0.f ? v : 0.f;     // relu(per-image mean)
    #pragma unroll
    for (int off = 32; off > 0; off >>= 1) v += __shfl_down(v, off, 64);
    if (t == 0) out[0] = v * (1.0f / 64.0f);
}

extern "C" void kernel_launch(void* const* d_in, const int* in_sizes, int n_in,
                              void* d_out, int out_size, void* d_ws, size_t ws_size,
                              hipStream_t stream)
{
    const float* pred   = (const float*)d_in[0];
    const float* target = (const float*)d_in[1];
    float* out = (float*)d_out;
    float* ws  = (float*)d_ws;

    hipMemsetAsync(ws, 0, 64 * sizeof(float), stream);  // ws poisoned 0xAA each call
    ssim_main<<<dim3(8, 64), 512, 0, stream>>>(pred, target, ws);
    ssim_finalize<<<1, 64, 0, stream>>>(ws, out);
}